// Round 8
// baseline (480.087 us; speedup 1.0000x reference)
//
#include <hip/hip_runtime.h>
#include <hip/hip_bf16.h>

// EnKF-LSTM (LS=1, BS=32, NH=256, NE=64, SEQ=64, DIN=256, MOBS=64)
// R7: k_lstm residency map — i+o gates register-resident (64 VGPR/lane),
// g gate LDS-resident (128 KB), stream ONLY f (128 KB/step/CU, half of R6).
// __launch_bounds__(1024,4) pins 4 waves/SIMD -> 128-VGPR cap; per-lane
// demand ~112 so residency actually sticks (R6 spilled at VGPR_Count=64,
// WRITE_SIZE 29 MB vs 2 ideal). k_fused unchanged from R6.

typedef _Float16 f16;
typedef _Float16 f16x8 __attribute__((ext_vector_type(8)));
typedef _Float16 h4 __attribute__((ext_vector_type(4)));
typedef float f32x4 __attribute__((ext_vector_type(4)));

#define BS   32
#define NH   256
#define NE   64
#define SEQQ 64
#define DIN  256
#define MOBS 64
#define G4   1024

__device__ __forceinline__ float fast_sigmoid(float x) {
  return __builtin_amdgcn_rcpf(1.f + __expf(-x));
}
__device__ __forceinline__ float fast_tanh(float x) {
  return 2.f * __builtin_amdgcn_rcpf(1.f + __expf(-2.f * x)) - 1.f;
}

// ---------------- K0: pack weights into MFMA fragment order ----------------
// Wpack[((tile*8+ks)*64+lane)*8+j] = W[(ks*32+(lane>>4)*8+j)*1024 + tile*16+(lane&15)]
__global__ __launch_bounds__(256)
void k_pack(const float* __restrict__ W_hh, const float* __restrict__ W_ih,
            const float* __restrict__ Wh, f16* __restrict__ Wpack,
            f16* __restrict__ WpackIh, f16* __restrict__ WhfP) {
  const int blk = blockIdx.x, tid = threadIdx.x;
  if (blk < 32) {
    const float* src = (blk & 1) ? W_ih : W_hh;
    f16* dst = (blk & 1) ? WpackIh : Wpack;
    const int kh = blk >> 1;  // k-rows [kh*16, kh*16+16)
    __shared__ f16 ls[16][1032];
    for (int idx = tid; idx < 16 * 1024; idx += 256) {
      int kr = idx >> 10, n2 = idx & 1023;
      ls[kr][n2] = (f16)src[(size_t)(kh * 16 + kr) * G4 + n2];
    }
    __syncthreads();
    const int ks = kh >> 1;
    const int lane = tid & 63;
    const int qd = lane >> 4, c0 = lane & 15;
    if ((qd >> 1) == (kh & 1)) {
      const int krow = (qd & 1) * 8;
      for (int tile = tid >> 6; tile < 64; tile += 4) {
        f16x8 v;
#pragma unroll
        for (int j = 0; j < 8; ++j) v[j] = ls[krow + j][tile * 16 + c0];
        *(f16x8*)&dst[(size_t)((tile * 8 + ks) * 64 + lane) * 8] = v;
      }
    }
  } else {
    for (int g = tid; g < 2048; g += 256) {
      int lane = g & 63, ks = (g >> 6) & 7, mt = g >> 9;
      int row = mt * 16 + (lane & 15);
      int k0 = ks * 32 + (lane >> 4) * 8;
#pragma unroll
      for (int j = 0; j < 8; ++j)
        WhfP[g * 8 + j] = (f16)Wh[row * NH + k0 + j];
    }
  }
}

// ---------------- K1: xwH = f16x4{i,f,g,o}(x @ W_ih + b) -------------------
// layout: xwH[((g4*64 + t)*16 + r)*256 + j]
__global__ __launch_bounds__(512, 2)
void k_xw(const float* __restrict__ x, const f16* __restrict__ WpackIh,
          const float* __restrict__ bv, h4* __restrict__ xwH) {
  __shared__ __align__(16) f16 xs[16 * 264];
  const int tid = threadIdx.x;
  const int m0 = blockIdx.x * 16;
  const int b = m0 >> 6, t0 = m0 & 63;
  const int g4 = b >> 4, br = b & 15;
  const int lane = tid & 63, w = tid >> 6;
  const int c0 = lane & 15, qd = lane >> 4;
  const int w0 = w * 32;
  for (int idx = tid; idx < 16 * 256; idx += 512) {
    int r = idx >> 8, k = idx & 255;
    xs[r * 264 + k] = (f16)x[(size_t)(m0 + r) * 256 + k];
  }
  __syncthreads();
  f16x8 afr[8];
#pragma unroll
  for (int ks = 0; ks < 8; ++ks)
    afr[ks] = *(const f16x8*)&xs[c0 * 264 + ks * 32 + qd * 8];
  const f16* wp0 = WpackIh + (size_t)lane * 8;
  f32x4 acc[8];
#pragma unroll
  for (int tt = 0; tt < 8; ++tt) {
    const int tg = ((tt >> 1) << 4) + w * 2 + (tt & 1);
    const f16* p = wp0 + (size_t)tg * 4096;
    f16x8 bf[8];
#pragma unroll
    for (int ks = 0; ks < 8; ++ks) bf[ks] = *(const f16x8*)(p + ks * 512);
    f32x4 a0 = {0.f, 0.f, 0.f, 0.f}, a1 = {0.f, 0.f, 0.f, 0.f};
#pragma unroll
    for (int ks = 0; ks < 8; ks += 2) {
      a0 = __builtin_amdgcn_mfma_f32_16x16x32_f16(afr[ks], bf[ks], a0, 0, 0, 0);
      a1 = __builtin_amdgcn_mfma_f32_16x16x32_f16(afr[ks + 1], bf[ks + 1], a1, 0, 0, 0);
    }
    acc[tt] = a0 + a1;
  }
#pragma unroll
  for (int nt = 0; nt < 2; ++nt) {
    const int j = w0 + nt * 16 + c0;
#pragma unroll
    for (int q = 0; q < 4; ++q) {
      const int t = t0 + qd * 4 + q;
      h4 v;
      v[0] = (f16)(acc[0 + nt][q] + bv[j]);
      v[1] = (f16)(acc[2 + nt][q] + bv[256 + j]);
      v[2] = (f16)(acc[4 + nt][q] + bv[512 + j]);
      v[3] = (f16)(acc[6 + nt][q] + bv[768 + j]);
      xwH[((size_t)(g4 * 64 + t) * 16 + br) * 256 + j] = v;
    }
  }
}

// ---------------- K2: LSTM recurrence --------------------------------------
// i,o register-resident; g LDS-resident; stream f only (bf dbuf).
template <bool LAST>
__device__ __forceinline__ void lstm_step(
    int t, const f16* hcur, f16* hnxt, const f16* wgf, const f16* gbase,
    const f16x8 (&wi)[8], const f16x8 (&wo)[8], int c0, int qd, int j, int b0,
    int e, const h4* xwbase, f16x8 (&bf)[2], float (&creg)[4],
    const float* __restrict__ eps_h, const float* __restrict__ eps_c,
    float nq, float nee, float* __restrict__ stateF2) {
  // xw loads first: independent, retire during the MFMA chain
  h4 xw[4];
#pragma unroll
  for (int q = 0; q < 4; ++q)
    xw[q] = xwbase[(size_t)(t * 16 + qd * 4 + q) * 256 + j];

  f32x4 acc0 = {0.f, 0.f, 0.f, 0.f}, acc1 = {0.f, 0.f, 0.f, 0.f};
  f32x4 acc2 = {0.f, 0.f, 0.f, 0.f}, acc3 = {0.f, 0.f, 0.f, 0.f};
#pragma unroll
  for (int ks = 0; ks < 8; ++ks) {
    f16x8 afr = *(const f16x8*)&hcur[c0 * 264 + ks * 32 + qd * 8];
    f16x8 gbf = *(const f16x8*)(gbase + ks * 512);
    const int k2 = (ks + 1) & 7;  // cyclic: ks=7 preloads ks=0 of next step
    bf[(ks + 1) & 1] = *(const f16x8*)(wgf + k2 * 512);
    acc0 = __builtin_amdgcn_mfma_f32_16x16x32_f16(afr, wi[ks], acc0, 0, 0, 0);
    acc1 = __builtin_amdgcn_mfma_f32_16x16x32_f16(afr, bf[ks & 1], acc1, 0, 0, 0);
    acc2 = __builtin_amdgcn_mfma_f32_16x16x32_f16(afr, gbf, acc2, 0, 0, 0);
    acc3 = __builtin_amdgcn_mfma_f32_16x16x32_f16(afr, wo[ks], acc3, 0, 0, 0);
  }

#pragma unroll
  for (int q = 0; q < 4; ++q) {
    const int r = qd * 4 + q;
    float iv = acc0[q] + (float)xw[q][0];
    float fv = acc1[q] + (float)xw[q][1];
    float gv = acc2[q] + (float)xw[q][2];
    float ov = acc3[q] + (float)xw[q][3];
    float c2 = fast_sigmoid(fv) * creg[q] + fast_sigmoid(iv) * fast_tanh(gv);
    float h2 = fast_sigmoid(ov) * fast_tanh(c2);
    creg[q] = c2;
    if (!LAST) {
      hnxt[r * 264 + j] = (f16)h2;
    } else {
      stateF2[((size_t)e * 32 + b0 + r) * 256 + j] =
          h2 + nq * eps_h[(e * BS + b0 + r) * NH + j];
      stateF2[((size_t)(32 + e) * 32 + b0 + r) * 256 + j] =
          c2 + nee * eps_c[(e * BS + b0 + r) * NH + j];
    }
  }
  if (!LAST) __syncthreads();
}

__global__ __launch_bounds__(1024, 4)
void k_lstm(const h4* __restrict__ xwH, const f16* __restrict__ Wpack,
            const float* __restrict__ enkf, const float* __restrict__ eps_h,
            const float* __restrict__ eps_c, const float* __restrict__ qp,
            const float* __restrict__ ep, float* __restrict__ stateF2) {
  __shared__ __align__(16) f16 glds[65536];   // 128 KB g-gate fragments
  __shared__ __align__(16) f16 hs[2][16 * 264];
  const int tid = threadIdx.x;
  const int e = blockIdx.x >> 1;
  const int g4 = blockIdx.x & 1;
  const int b0 = g4 * 16;
  const int lane = tid & 63;
  const int ws = tid >> 6;
  const int c0 = lane & 15;
  const int qd = lane >> 4;
  const int j = ws * 16 + c0;

  // fill g-gate LDS (tiles 32..47 of Wpack, straight copy)
  {
    const f16* gsrc = Wpack + 32 * 4096;
    for (int i = tid; i < 8192; i += 1024)
      *(f16x8*)&glds[i * 8] = *(const f16x8*)&gsrc[(size_t)i * 8];
  }
  // i-gate and o-gate tiles register-resident (tiles ws and 48+ws)
  f16x8 wi[8], wo[8];
  {
    const f16* ip = Wpack + (size_t)(0 + ws) * 4096 + (size_t)lane * 8;
    const f16* op = Wpack + (size_t)(48 + ws) * 4096 + (size_t)lane * 8;
#pragma unroll
    for (int ks = 0; ks < 8; ++ks) {
      wi[ks] = *(const f16x8*)(ip + ks * 512);
      wo[ks] = *(const f16x8*)(op + ks * 512);
    }
  }
  for (int idx = tid; idx < 16 * 256; idx += 1024) {
    int r = idx >> 8, nh = idx & 255;
    hs[0][r * 264 + nh] = (f16)enkf[((b0 + r) * NH + nh) * NE + e];
  }
  float creg[4];
#pragma unroll
  for (int q = 0; q < 4; ++q)
    creg[q] = enkf[((b0 + qd * 4 + q) * NH + j) * NE + 32 + e];

  const float nq = fabsf(qp[0]);
  const float nee = fabsf(ep[0]);

  const f16* wgf = Wpack + (size_t)(16 + ws) * 4096 + (size_t)lane * 8;  // f gate (streamed)
  const f16* gbase = glds + (size_t)ws * 4096 + (size_t)lane * 8;

  f16x8 bf[2];
  bf[0] = *(const f16x8*)(wgf);

  const h4* xwbase = xwH + (size_t)g4 * 64 * 16 * 256;
  __syncthreads();

  for (int t = 0; t < 62; t += 2) {
    lstm_step<false>(t, hs[0], hs[1], wgf, gbase, wi, wo, c0, qd, j, b0, e,
                     xwbase, bf, creg, eps_h, eps_c, nq, nee, stateF2);
    lstm_step<false>(t + 1, hs[1], hs[0], wgf, gbase, wi, wo, c0, qd, j, b0, e,
                     xwbase, bf, creg, eps_h, eps_c, nq, nee, stateF2);
  }
  lstm_step<false>(62, hs[0], hs[1], wgf, gbase, wi, wo, c0, qd, j, b0, e,
                   xwbase, bf, creg, eps_h, eps_c, nq, nee, stateF2);
  lstm_step<true>(63, hs[1], hs[0], wgf, gbase, wi, wo, c0, qd, j, b0, e,
                  xwbase, bf, creg, eps_h, eps_c, nq, nee, stateF2);
}

// ---------------- K3: fused tail (per-batch) --------------------------------
// stateF2 layout: [(slot j)*32 + b]*256 + nh
__global__ __launch_bounds__(256)
void k_fused(const float* __restrict__ stateF2, const f16* __restrict__ WhfP,
             const float* __restrict__ bh, const float* __restrict__ rp,
             const float* __restrict__ y, float* __restrict__ mu_out,
             float* __restrict__ sig_out, float* __restrict__ state_out,
             float* __restrict__ quad_g, float* __restrict__ logdet_g) {
  __shared__ __align__(16) f16 stT[64 * 264];
  __shared__ float hxl[64 * 66];
  __shared__ float Pm[64 * 65];
  __shared__ __align__(16) f16 TT[64 * 72];
  __shared__ __align__(16) char U[36864];
  __shared__ float hxm[64];
  __shared__ float dinv[64];
  __shared__ float srm[256];

  const int tid = threadIdx.x, b = blockIdx.x;
  const int lane = tid & 63, wave = tid >> 6;
  const int c0 = lane & 15, qd = lane >> 4;
  const int n = tid & 63, mg = tid >> 6;
  const float r2 = rp[0] * rp[0];

  f16x8 whfr[8];
#pragma unroll
  for (int ks = 0; ks < 8; ++ks)
    whfr[ks] = *(const f16x8*)&WhfP[(((size_t)wave * 8 + ks) * 64 + lane) * 8];

  // ---- phase 1: hxi ; mean ; HA ; P
  for (int idx = tid; idx < NH * NE; idx += 256) {
    int j = idx >> 8, k = idx & 255;
    stT[j * 264 + k] = (f16)stateF2[((size_t)j * 32 + b) * 256 + k];
  }
  __syncthreads();
  for (int nt = 0; nt < 4; ++nt) {
    f32x4 acc = {0.f, 0.f, 0.f, 0.f};
#pragma unroll
    for (int ks = 0; ks < 8; ++ks) {
      f16x8 bfr = *(const f16x8*)&stT[(nt * 16 + c0) * 264 + ks * 32 + qd * 8];
      acc = __builtin_amdgcn_mfma_f32_16x16x32_f16(whfr[ks], bfr, acc, 0, 0, 0);
    }
#pragma unroll
    for (int q = 0; q < 4; ++q)
      hxl[(wave * 16 + qd * 4 + q) * 66 + nt * 16 + c0] = acc[q] + bh[wave * 16 + qd * 4 + q];
  }
  __syncthreads();
  if (tid < 64) {
    float s = 0.f;
    for (int j = 0; j < 64; ++j) s += hxl[tid * 66 + j];
    hxm[tid] = s * (1.f / 64.f);
  }
  __syncthreads();
  {
    f16* HAf = (f16*)U;
    for (int idx = tid; idx < 4096; idx += 256) {
      int m = idx >> 6, j = idx & 63;
      HAf[m * 72 + j] = (f16)(hxl[m * 66 + j] - hxm[m]);
    }
    __syncthreads();
    f16x8 afr[2];
#pragma unroll
    for (int ks = 0; ks < 2; ++ks)
      afr[ks] = *(const f16x8*)&HAf[(wave * 16 + c0) * 72 + ks * 32 + qd * 8];
    for (int nt = 0; nt < 4; ++nt) {
      f32x4 acc = {0.f, 0.f, 0.f, 0.f};
#pragma unroll
      for (int ks = 0; ks < 2; ++ks) {
        f16x8 bfr = *(const f16x8*)&HAf[(nt * 16 + c0) * 72 + ks * 32 + qd * 8];
        acc = __builtin_amdgcn_mfma_f32_16x16x32_f16(afr[ks], bfr, acc, 0, 0, 0);
      }
#pragma unroll
      for (int q = 0; q < 4; ++q) {
        int m1 = wave * 16 + qd * 4 + q, m2 = nt * 16 + c0;
        Pm[m1 * 65 + m2] = acc[q] * (1.f / 63.f) + (m1 == m2 ? r2 : 0.f);
      }
    }
  }
  __syncthreads();

  // ---- phase 2: LDL^T factor + blocked 64-RHS solve + T = HA^T sol
  {
    float* R = (float*)U;
    f16* HAT = (f16*)(U + 16384);
    f16* solT = (f16*)(U + 25600);
    for (int idx = tid; idx < 4096; idx += 256) {
      int m = idx >> 6, j = idx & 63;
      float hv = hxl[m * 66 + j];
      R[idx] = y[b * 64 + m] - hv;
      HAT[j * 72 + m] = (f16)(hv - hxm[m]);
    }
    __syncthreads();
    // factor (rank-1 per column)
    for (int k = 0; k < 64; ++k) {
      float dk = Pm[k * 65 + k];
      if (n > k) {
        float f = Pm[n * 65 + k] * __builtin_amdgcn_rcpf(dk);
        for (int m = k + 1 + mg; m < 64; m += 4)
          Pm[m * 65 + n] -= Pm[m * 65 + k] * f;
      }
      __syncthreads();
    }
    if (tid < 64) dinv[tid] = __builtin_amdgcn_rcpf(Pm[tid * 65 + tid]);
    __syncthreads();
    // forward (unit-L), 8-col blocks
    for (int i0 = 0; i0 < 64; i0 += 8) {
      if (wave == 0) {
        float rl[8];
#pragma unroll
        for (int d = 0; d < 8; ++d) rl[d] = R[(i0 + d) * 64 + n];
#pragma unroll
        for (int a = 1; a < 8; ++a)
#pragma unroll
          for (int bq = 0; bq < a; ++bq)
            rl[a] -= Pm[(i0 + a) * 65 + i0 + bq] * dinv[i0 + bq] * rl[bq];
#pragma unroll
        for (int d = 1; d < 8; ++d) R[(i0 + d) * 64 + n] = rl[d];
      }
      __syncthreads();
      for (int m = i0 + 8 + mg; m < 64; m += 4) {
        float s = R[m * 64 + n];
#pragma unroll
        for (int d = 0; d < 8; ++d)
          s -= Pm[m * 65 + i0 + d] * dinv[i0 + d] * R[(i0 + d) * 64 + n];
        R[m * 64 + n] = s;
      }
      __syncthreads();
    }
    for (int idx = tid; idx < 4096; idx += 256) R[idx] *= dinv[idx >> 6];
    __syncthreads();
    // backward (L^T), 8-col blocks descending
    for (int i0 = 56; i0 >= 0; i0 -= 8) {
      if (wave == 0) {
        float rl[8];
#pragma unroll
        for (int d = 0; d < 8; ++d) rl[d] = R[(i0 + d) * 64 + n];
#pragma unroll
        for (int a = 6; a >= 0; --a)
#pragma unroll
          for (int bq = 7; bq > a; --bq)
            rl[a] -= Pm[(i0 + bq) * 65 + i0 + a] * dinv[i0 + a] * rl[bq];
#pragma unroll
        for (int d = 0; d < 7; ++d) R[(i0 + d) * 64 + n] = rl[d];
      }
      __syncthreads();
      for (int m = mg; m < i0; m += 4) {
        float s = R[m * 64 + n];
        float dm = dinv[m];
#pragma unroll
        for (int d = 0; d < 8; ++d)
          s -= Pm[(i0 + d) * 65 + m] * dm * R[(i0 + d) * 64 + n];
        R[m * 64 + n] = s;
      }
      __syncthreads();
    }
    for (int idx = tid; idx < 4096; idx += 256) {
      int m = idx >> 6, j = idx & 63;
      solT[j * 72 + m] = (f16)R[m * 64 + j];
    }
    __syncthreads();
    f16x8 afr[2];
#pragma unroll
    for (int ks = 0; ks < 2; ++ks)
      afr[ks] = *(const f16x8*)&HAT[(wave * 16 + c0) * 72 + ks * 32 + qd * 8];
    for (int nt = 0; nt < 4; ++nt) {
      f32x4 acc = {0.f, 0.f, 0.f, 0.f};
#pragma unroll
      for (int ks = 0; ks < 2; ++ks) {
        f16x8 bfr = *(const f16x8*)&solT[(nt * 16 + c0) * 72 + ks * 32 + qd * 8];
        acc = __builtin_amdgcn_mfma_f32_16x16x32_f16(afr[ks], bfr, acc, 0, 0, 0);
      }
#pragma unroll
      for (int q = 0; q < 4; ++q) {
        int jp = wave * 16 + qd * 4 + q, j = nt * 16 + c0;
        TT[j * 72 + jp] = (f16)(acc[q] * (1.f / 63.f));
      }
    }
  }
  __syncthreads();

  // ---- phase 3: state_out = stateF + A @ TT
  {
    f16* Af = (f16*)U;
    for (int idx = tid; idx < NH * NE; idx += 256) {
      int j = idx >> 8, k = idx & 255;
      Af[k * 72 + j] = (f16)stateF2[((size_t)j * 32 + b) * 256 + k];
    }
    __syncthreads();
    {
      float s = 0.f;
      for (int j = 0; j < 64; ++j) s += (float)Af[tid * 72 + j];
      srm[tid] = s * (1.f / 64.f);
    }
    __syncthreads();
    for (int idx = tid; idx < NH * NE; idx += 256) {
      int nh = idx >> 6, j = idx & 63;
      Af[nh * 72 + j] = (f16)((float)Af[nh * 72 + j] - srm[nh]);
    }
    __syncthreads();
    f16x8 bfr[4][2];
#pragma unroll
    for (int nt = 0; nt < 4; ++nt)
#pragma unroll
      for (int ks = 0; ks < 2; ++ks)
        bfr[nt][ks] = *(const f16x8*)&TT[(nt * 16 + c0) * 72 + ks * 32 + qd * 8];
    for (int mt0 = 0; mt0 < 4; ++mt0) {
      int mt = wave * 4 + mt0;
      f16x8 afr[2];
#pragma unroll
      for (int ks = 0; ks < 2; ++ks)
        afr[ks] = *(const f16x8*)&Af[(mt * 16 + c0) * 72 + ks * 32 + qd * 8];
#pragma unroll
      for (int nt = 0; nt < 4; ++nt) {
        f32x4 acc = {0.f, 0.f, 0.f, 0.f};
#pragma unroll
        for (int ks = 0; ks < 2; ++ks)
          acc = __builtin_amdgcn_mfma_f32_16x16x32_f16(afr[ks], bfr[nt][ks], acc, 0, 0, 0);
#pragma unroll
        for (int q = 0; q < 4; ++q) {
          int m = mt * 16 + qd * 4 + q, j = nt * 16 + c0;
          float v = (float)Af[m * 72 + j] + srm[m] + acc[q];
          state_out[b * (NH * NE) + m * 64 + j] = v;
          stT[j * 264 + m] = (f16)v;
        }
      }
    }
  }
  __syncthreads();

  // ---- phase 4: mu/sig on updated state
  for (int nt = 0; nt < 4; ++nt) {
    f32x4 acc = {0.f, 0.f, 0.f, 0.f};
#pragma unroll
    for (int ks = 0; ks < 8; ++ks) {
      f16x8 bfr = *(const f16x8*)&stT[(nt * 16 + c0) * 264 + ks * 32 + qd * 8];
      acc = __builtin_amdgcn_mfma_f32_16x16x32_f16(whfr[ks], bfr, acc, 0, 0, 0);
    }
#pragma unroll
    for (int q = 0; q < 4; ++q)
      hxl[(wave * 16 + qd * 4 + q) * 66 + nt * 16 + c0] = acc[q] + bh[wave * 16 + qd * 4 + q];
  }
  __syncthreads();
  if (tid < 64) {
    float s = 0.f;
    for (int j = 0; j < 64; ++j) s += hxl[tid * 66 + j];
    s *= (1.f / 64.f);
    hxm[tid] = s;
    mu_out[b * MOBS + tid] = s;
  }
  __syncthreads();
  {
    f16* HAf = (f16*)U;
    for (int idx = tid; idx < 4096; idx += 256) {
      int m = idx >> 6, j = idx & 63;
      HAf[m * 72 + j] = (f16)(hxl[m * 66 + j] - hxm[m]);
    }
    __syncthreads();
    f16x8 afr[2];
#pragma unroll
    for (int ks = 0; ks < 2; ++ks)
      afr[ks] = *(const f16x8*)&HAf[(wave * 16 + c0) * 72 + ks * 32 + qd * 8];
    for (int nt = 0; nt < 4; ++nt) {
      f32x4 acc = {0.f, 0.f, 0.f, 0.f};
#pragma unroll
      for (int ks = 0; ks < 2; ++ks) {
        f16x8 bfr = *(const f16x8*)&HAf[(nt * 16 + c0) * 72 + ks * 32 + qd * 8];
        acc = __builtin_amdgcn_mfma_f32_16x16x32_f16(afr[ks], bfr, acc, 0, 0, 0);
      }
#pragma unroll
      for (int q = 0; q < 4; ++q) {
        int m1 = wave * 16 + qd * 4 + q, m2 = nt * 16 + c0;
        float v = acc[q] * (1.f / 63.f) + (m1 == m2 ? r2 : 0.f);
        sig_out[b * (MOBS * MOBS) + m1 * MOBS + m2] = v;
        Pm[m1 * 65 + m2] = v + (m1 == m2 ? 1e-6f : 0.f);
      }
    }
  }
  __syncthreads();

  // ---- phase 5: loglik — factor (barriers), then wave-sync shfl solve
  for (int k = 0; k < 64; ++k) {
    float dk = Pm[k * 65 + k];
    if (n > k) {
      float f = Pm[n * 65 + k] * __builtin_amdgcn_rcpf(dk);
      for (int m = k + 1 + mg; m < 64; m += 4)
        Pm[m * 65 + n] -= Pm[m * 65 + k] * f;
    }
    __syncthreads();
  }
  if (tid < 64) dinv[tid] = __builtin_amdgcn_rcpf(Pm[tid * 65 + tid]);
  __syncthreads();
  if (wave == 0) {
    const int m = lane;
    float rm = y[b * 64 + m] - hxm[m];
    const float r0 = rm;
    for (int i = 0; i < 63; ++i) {
      float xi = __shfl(rm, i);
      if (m > i) rm -= Pm[m * 65 + i] * dinv[i] * xi;
    }
    rm *= dinv[m];
    for (int i = 63; i >= 1; --i) {
      float xi = __shfl(rm, i);
      if (m < i) rm -= Pm[i * 65 + m] * dinv[m] * xi;
    }
    float prod = r0 * rm;
    float ld = __logf(Pm[m * 65 + m]);
#pragma unroll
    for (int off = 32; off; off >>= 1) {
      prod += __shfl_down(prod, off);
      ld += __shfl_down(ld, off);
    }
    if (m == 0) {
      quad_g[b] = prod;
      logdet_g[b] = ld;
    }
  }
}

// ---------------- K4: final reduction ---------------------------------------
__global__ __launch_bounds__(64)
void k_reduce(const float* __restrict__ quad_g, const float* __restrict__ logdet_g,
              float* __restrict__ out_l, float* __restrict__ out_nis) {
  if (threadIdx.x == 0 && blockIdx.x == 0) {
    float l = 0.f, qs = 0.f;
    for (int b2 = 0; b2 < 32; ++b2) {
      l += -0.5f * (logdet_g[b2] + quad_g[b2]);
      qs += quad_g[b2];
    }
    out_l[0] = l;
    out_nis[0] = qs * (1.f / 32.f);
  }
}

extern "C" void kernel_launch(void* const* d_in, const int* in_sizes, int n_in,
                              void* d_out, int out_size, void* d_ws, size_t ws_size,
                              hipStream_t stream) {
  (void)in_sizes; (void)n_in; (void)out_size; (void)ws_size;
  const float* x     = (const float*)d_in[0];
  const float* y     = (const float*)d_in[1];
  const float* enkf  = (const float*)d_in[2];
  const float* W_ih  = (const float*)d_in[3];
  const float* W_hh  = (const float*)d_in[4];
  const float* bvec  = (const float*)d_in[5];
  const float* Wh    = (const float*)d_in[6];
  const float* bh    = (const float*)d_in[7];
  const float* qp    = (const float*)d_in[8];
  const float* ep    = (const float*)d_in[9];
  const float* rp    = (const float*)d_in[10];
  const float* eps_h = (const float*)d_in[11];
  const float* eps_c = (const float*)d_in[12];

  char* ws = (char*)d_ws;
  h4*    xwH     = (h4*)(ws);                   // 4,194,304
  f16*   Wpack   = (f16*)(ws + 4194304);        //   524,288
  f16*   WpackIh = (f16*)(ws + 4718592);        //   524,288
  f16*   WhfP    = (f16*)(ws + 5242880);        //    32,768
  float* stateF2 = (float*)(ws + 5275648);      // 2,097,152
  float* quadg   = (float*)(ws + 7372800);      //       128
  float* ldg     = (float*)(ws + 7372928);      //       128

  float* out = (float*)d_out;
  float* mu_out    = out;           // 2048
  float* sig_out   = out + 2048;    // 131072
  float* state_out = out + 133120;  // 524288
  float* l_out     = out + 657408;
  float* nis_out   = out + 657409;

  k_pack<<<33, 256, 0, stream>>>(W_hh, W_ih, Wh, Wpack, WpackIh, WhfP);
  k_xw<<<128, 512, 0, stream>>>(x, WpackIh, bvec, xwH);
  k_lstm<<<64, 1024, 0, stream>>>(xwH, Wpack, enkf, eps_h, eps_c, qp, ep, stateF2);
  k_fused<<<32, 256, 0, stream>>>(stateF2, WhfP, bh, rp, y, mu_out, sig_out,
                                  state_out, quadg, ldg);
  k_reduce<<<1, 64, 0, stream>>>(quadg, ldg, l_out, nis_out);
}

// Round 9
// 416.077 us; speedup vs baseline: 1.1538x; 1.1538x over previous
//
#include <hip/hip_runtime.h>
#include <hip/hip_bf16.h>

// EnKF-LSTM (LS=1, BS=32, NH=256, NE=64, SEQ=64, DIN=256, MOBS=64)
// R8: k_lstm reverted to R6 (best measured: g-gate LDS-resident, o-gate
// register tile, stream i,f; 253 us). Tail work: 8-col blocked LDL^T factor
// (16 barriers vs 64, x2 sites) in k_fused; k_reduce folded into k_fused via
// atomicAdd (k_pack zero-inits l/nis outputs each call).

typedef _Float16 f16;
typedef _Float16 f16x8 __attribute__((ext_vector_type(8)));
typedef _Float16 h4 __attribute__((ext_vector_type(4)));
typedef float f32x4 __attribute__((ext_vector_type(4)));

#define BS   32
#define NH   256
#define NE   64
#define SEQQ 64
#define DIN  256
#define MOBS 64
#define G4   1024

__device__ __forceinline__ float fast_sigmoid(float x) {
  return __builtin_amdgcn_rcpf(1.f + __expf(-x));
}
__device__ __forceinline__ float fast_tanh(float x) {
  return 2.f * __builtin_amdgcn_rcpf(1.f + __expf(-2.f * x)) - 1.f;
}

// Blocked LDL^T factor (in-place on Pm[64][65], lower triangle + diagonal
// valid on exit). 8-col panels: wave0 factors panel via shfl (no barriers),
// all waves do rank-8 trailing update. ~16 barriers total.
__device__ __forceinline__ void ldl_factor8(float* Pm, int tid) {
  const int lane = tid & 63, wave = tid >> 6;
  for (int kb = 0; kb < 64; kb += 8) {
    if (wave == 0) {
      float rl[8];
#pragma unroll
      for (int d = 0; d < 8; ++d) rl[d] = Pm[lane * 65 + kb + d];
#pragma unroll
      for (int kk = 0; kk < 8; ++kk) {
        float dk = __shfl(rl[kk], kb + kk);
        float fm = rl[kk] * __builtin_amdgcn_rcpf(dk);
#pragma unroll
        for (int jj = kk + 1; jj < 8; ++jj) {
          float cj = __shfl(rl[kk], kb + jj);
          if (lane > kb + kk) rl[jj] -= fm * cj;
        }
      }
#pragma unroll
      for (int d = 0; d < 8; ++d)
        if (lane >= kb) Pm[lane * 65 + kb + d] = rl[d];
    }
    __syncthreads();
    if (kb < 56) {
      const int n = lane;
      if (n >= kb + 8) {
        float ln[8];
#pragma unroll
        for (int d = 0; d < 8; ++d)
          ln[d] = Pm[n * 65 + kb + d] *
                  __builtin_amdgcn_rcpf(Pm[(kb + d) * 65 + kb + d]);
        for (int m = kb + 8 + wave; m < 64; m += 4) {
          float s = Pm[m * 65 + n];
#pragma unroll
          for (int d = 0; d < 8; ++d) s -= Pm[m * 65 + kb + d] * ln[d];
          Pm[m * 65 + n] = s;
        }
      }
      __syncthreads();
    }
  }
}

// ---------------- K0: pack weights into MFMA fragment order ----------------
__global__ __launch_bounds__(256)
void k_pack(const float* __restrict__ W_hh, const float* __restrict__ W_ih,
            const float* __restrict__ Wh, f16* __restrict__ Wpack,
            f16* __restrict__ WpackIh, f16* __restrict__ WhfP,
            float* __restrict__ l_out, float* __restrict__ nis_out) {
  const int blk = blockIdx.x, tid = threadIdx.x;
  if (blk < 32) {
    const float* src = (blk & 1) ? W_ih : W_hh;
    f16* dst = (blk & 1) ? WpackIh : Wpack;
    const int kh = blk >> 1;  // k-rows [kh*16, kh*16+16)
    __shared__ f16 ls[16][1032];
    for (int idx = tid; idx < 16 * 1024; idx += 256) {
      int kr = idx >> 10, n2 = idx & 1023;
      ls[kr][n2] = (f16)src[(size_t)(kh * 16 + kr) * G4 + n2];
    }
    __syncthreads();
    const int ks = kh >> 1;
    const int lane = tid & 63;
    const int qd = lane >> 4, c0 = lane & 15;
    if ((qd >> 1) == (kh & 1)) {
      const int krow = (qd & 1) * 8;
      for (int tile = tid >> 6; tile < 64; tile += 4) {
        f16x8 v;
#pragma unroll
        for (int j = 0; j < 8; ++j) v[j] = ls[krow + j][tile * 16 + c0];
        *(f16x8*)&dst[(size_t)((tile * 8 + ks) * 64 + lane) * 8] = v;
      }
    }
  } else {
    if (tid == 0) { l_out[0] = 0.f; nis_out[0] = 0.f; }
    for (int g = tid; g < 2048; g += 256) {
      int lane = g & 63, ks = (g >> 6) & 7, mt = g >> 9;
      int row = mt * 16 + (lane & 15);
      int k0 = ks * 32 + (lane >> 4) * 8;
#pragma unroll
      for (int j = 0; j < 8; ++j)
        WhfP[g * 8 + j] = (f16)Wh[row * NH + k0 + j];
    }
  }
}

// ---------------- K1: xwH = f16x4{i,f,g,o}(x @ W_ih + b) -------------------
// layout: xwH[((g4*64 + t)*16 + r)*256 + j]
__global__ __launch_bounds__(512, 2)
void k_xw(const float* __restrict__ x, const f16* __restrict__ WpackIh,
          const float* __restrict__ bv, h4* __restrict__ xwH) {
  __shared__ __align__(16) f16 xs[16 * 264];
  const int tid = threadIdx.x;
  const int m0 = blockIdx.x * 16;
  const int b = m0 >> 6, t0 = m0 & 63;
  const int g4 = b >> 4, br = b & 15;
  const int lane = tid & 63, w = tid >> 6;
  const int c0 = lane & 15, qd = lane >> 4;
  const int w0 = w * 32;
  for (int idx = tid; idx < 16 * 256; idx += 512) {
    int r = idx >> 8, k = idx & 255;
    xs[r * 264 + k] = (f16)x[(size_t)(m0 + r) * 256 + k];
  }
  __syncthreads();
  f16x8 afr[8];
#pragma unroll
  for (int ks = 0; ks < 8; ++ks)
    afr[ks] = *(const f16x8*)&xs[c0 * 264 + ks * 32 + qd * 8];
  const f16* wp0 = WpackIh + (size_t)lane * 8;
  f32x4 acc[8];
#pragma unroll
  for (int tt = 0; tt < 8; ++tt) {
    const int tg = ((tt >> 1) << 4) + w * 2 + (tt & 1);
    const f16* p = wp0 + (size_t)tg * 4096;
    f16x8 bf[8];
#pragma unroll
    for (int ks = 0; ks < 8; ++ks) bf[ks] = *(const f16x8*)(p + ks * 512);
    f32x4 a0 = {0.f, 0.f, 0.f, 0.f}, a1 = {0.f, 0.f, 0.f, 0.f};
#pragma unroll
    for (int ks = 0; ks < 8; ks += 2) {
      a0 = __builtin_amdgcn_mfma_f32_16x16x32_f16(afr[ks], bf[ks], a0, 0, 0, 0);
      a1 = __builtin_amdgcn_mfma_f32_16x16x32_f16(afr[ks + 1], bf[ks + 1], a1, 0, 0, 0);
    }
    acc[tt] = a0 + a1;
  }
#pragma unroll
  for (int nt = 0; nt < 2; ++nt) {
    const int j = w0 + nt * 16 + c0;
#pragma unroll
    for (int q = 0; q < 4; ++q) {
      const int t = t0 + qd * 4 + q;
      h4 v;
      v[0] = (f16)(acc[0 + nt][q] + bv[j]);
      v[1] = (f16)(acc[2 + nt][q] + bv[256 + j]);
      v[2] = (f16)(acc[4 + nt][q] + bv[512 + j]);
      v[3] = (f16)(acc[6 + nt][q] + bv[768 + j]);
      xwH[((size_t)(g4 * 64 + t) * 16 + br) * 256 + j] = v;
    }
  }
}

// ---------------- K2: LSTM recurrence (R6 config) ---------------------------
// streams i,f from L2 (bf dbuf); g from LDS; o register-resident.
template <bool LAST>
__device__ __forceinline__ void lstm_step(
    int t, const f16* hcur, f16* hnxt, const f16* wg0, const f16* wg1,
    const f16* gbase, const f16x8 (&wres)[8], int c0, int qd, int j, int b0,
    int e, const h4* xwbase, f16x8 (&bf)[2][2], float (&creg)[4],
    const float* __restrict__ eps_h, const float* __restrict__ eps_c,
    float nq, float nee, float* __restrict__ stateF2) {
  h4 xw[4];
#pragma unroll
  for (int q = 0; q < 4; ++q)
    xw[q] = xwbase[(size_t)(t * 16 + qd * 4 + q) * 256 + j];

  f32x4 acc0 = {0.f, 0.f, 0.f, 0.f}, acc1 = {0.f, 0.f, 0.f, 0.f};
  f32x4 acc2 = {0.f, 0.f, 0.f, 0.f}, acc3 = {0.f, 0.f, 0.f, 0.f};
#pragma unroll
  for (int ks = 0; ks < 8; ++ks) {
    f16x8 afr = *(const f16x8*)&hcur[c0 * 264 + ks * 32 + qd * 8];
    f16x8 gbf = *(const f16x8*)(gbase + ks * 512);
    const int k2 = (ks + 1) & 7;  // cyclic: ks=7 preloads ks=0 of next step
    bf[(ks + 1) & 1][0] = *(const f16x8*)(wg0 + k2 * 512);
    bf[(ks + 1) & 1][1] = *(const f16x8*)(wg1 + k2 * 512);
    acc0 = __builtin_amdgcn_mfma_f32_16x16x32_f16(afr, bf[ks & 1][0], acc0, 0, 0, 0);
    acc1 = __builtin_amdgcn_mfma_f32_16x16x32_f16(afr, bf[ks & 1][1], acc1, 0, 0, 0);
    acc2 = __builtin_amdgcn_mfma_f32_16x16x32_f16(afr, gbf, acc2, 0, 0, 0);
    acc3 = __builtin_amdgcn_mfma_f32_16x16x32_f16(afr, wres[ks], acc3, 0, 0, 0);
  }

#pragma unroll
  for (int q = 0; q < 4; ++q) {
    const int r = qd * 4 + q;
    float iv = acc0[q] + (float)xw[q][0];
    float fv = acc1[q] + (float)xw[q][1];
    float gv = acc2[q] + (float)xw[q][2];
    float ov = acc3[q] + (float)xw[q][3];
    float c2 = fast_sigmoid(fv) * creg[q] + fast_sigmoid(iv) * fast_tanh(gv);
    float h2 = fast_sigmoid(ov) * fast_tanh(c2);
    creg[q] = c2;
    if (!LAST) {
      hnxt[r * 264 + j] = (f16)h2;
    } else {
      stateF2[((size_t)e * 32 + b0 + r) * 256 + j] =
          h2 + nq * eps_h[(e * BS + b0 + r) * NH + j];
      stateF2[((size_t)(32 + e) * 32 + b0 + r) * 256 + j] =
          c2 + nee * eps_c[(e * BS + b0 + r) * NH + j];
    }
  }
  if (!LAST) __syncthreads();
}

__global__ __launch_bounds__(1024)
void k_lstm(const h4* __restrict__ xwH, const f16* __restrict__ Wpack,
            const float* __restrict__ enkf, const float* __restrict__ eps_h,
            const float* __restrict__ eps_c, const float* __restrict__ qp,
            const float* __restrict__ ep, float* __restrict__ stateF2) {
  __shared__ __align__(16) f16 glds[65536];   // 128 KB g-gate fragments
  __shared__ __align__(16) f16 hs[2][16 * 264];
  const int tid = threadIdx.x;
  const int e = blockIdx.x >> 1;
  const int g4 = blockIdx.x & 1;
  const int b0 = g4 * 16;
  const int lane = tid & 63;
  const int ws = tid >> 6;
  const int c0 = lane & 15;
  const int qd = lane >> 4;
  const int j = ws * 16 + c0;

  {
    const f16* gsrc = Wpack + 32 * 4096;
    for (int i = tid; i < 8192; i += 1024)
      *(f16x8*)&glds[i * 8] = *(const f16x8*)&gsrc[(size_t)i * 8];
  }
  // o-gate tile register-resident (tile 48+ws, 8 KB per wave)
  f16x8 wres[8];
  {
    const f16* op = Wpack + (size_t)(48 + ws) * 4096 + (size_t)lane * 8;
#pragma unroll
    for (int ks = 0; ks < 8; ++ks) wres[ks] = *(const f16x8*)(op + ks * 512);
  }
  for (int idx = tid; idx < 16 * 256; idx += 1024) {
    int r = idx >> 8, nh = idx & 255;
    hs[0][r * 264 + nh] = (f16)enkf[((b0 + r) * NH + nh) * NE + e];
  }
  float creg[4];
#pragma unroll
  for (int q = 0; q < 4; ++q)
    creg[q] = enkf[((b0 + qd * 4 + q) * NH + j) * NE + 32 + e];

  const float nq = fabsf(qp[0]);
  const float nee = fabsf(ep[0]);

  const f16* wg0 = Wpack + (size_t)(0 * 16 + ws) * 4096 + (size_t)lane * 8;
  const f16* wg1 = Wpack + (size_t)(1 * 16 + ws) * 4096 + (size_t)lane * 8;
  const f16* gbase = glds + (size_t)ws * 4096 + (size_t)lane * 8;

  f16x8 bf[2][2];
  bf[0][0] = *(const f16x8*)(wg0);
  bf[0][1] = *(const f16x8*)(wg1);

  const h4* xwbase = xwH + (size_t)g4 * 64 * 16 * 256;
  __syncthreads();

  for (int t = 0; t < 62; t += 2) {
    lstm_step<false>(t, hs[0], hs[1], wg0, wg1, gbase, wres, c0, qd, j, b0, e,
                     xwbase, bf, creg, eps_h, eps_c, nq, nee, stateF2);
    lstm_step<false>(t + 1, hs[1], hs[0], wg0, wg1, gbase, wres, c0, qd, j, b0,
                     e, xwbase, bf, creg, eps_h, eps_c, nq, nee, stateF2);
  }
  lstm_step<false>(62, hs[0], hs[1], wg0, wg1, gbase, wres, c0, qd, j, b0, e,
                   xwbase, bf, creg, eps_h, eps_c, nq, nee, stateF2);
  lstm_step<true>(63, hs[1], hs[0], wg0, wg1, gbase, wres, c0, qd, j, b0, e,
                  xwbase, bf, creg, eps_h, eps_c, nq, nee, stateF2);
}

// ---------------- K3: fused tail (per-batch) --------------------------------
// stateF2 layout: [(slot j)*32 + b]*256 + nh
__global__ __launch_bounds__(256)
void k_fused(const float* __restrict__ stateF2, const f16* __restrict__ WhfP,
             const float* __restrict__ bh, const float* __restrict__ rp,
             const float* __restrict__ y, float* __restrict__ mu_out,
             float* __restrict__ sig_out, float* __restrict__ state_out,
             float* __restrict__ l_out, float* __restrict__ nis_out) {
  __shared__ __align__(16) f16 stT[64 * 264];
  __shared__ float hxl[64 * 66];
  __shared__ float Pm[64 * 65];
  __shared__ __align__(16) f16 TT[64 * 72];
  __shared__ __align__(16) char U[36864];
  __shared__ float hxm[64];
  __shared__ float dinv[64];
  __shared__ float srm[256];

  const int tid = threadIdx.x, b = blockIdx.x;
  const int lane = tid & 63, wave = tid >> 6;
  const int c0 = lane & 15, qd = lane >> 4;
  const int n = tid & 63, mg = tid >> 6;
  const float r2 = rp[0] * rp[0];

  f16x8 whfr[8];
#pragma unroll
  for (int ks = 0; ks < 8; ++ks)
    whfr[ks] = *(const f16x8*)&WhfP[(((size_t)wave * 8 + ks) * 64 + lane) * 8];

  // ---- phase 1: hxi ; mean ; HA ; P
  for (int idx = tid; idx < NH * NE; idx += 256) {
    int j = idx >> 8, k = idx & 255;
    stT[j * 264 + k] = (f16)stateF2[((size_t)j * 32 + b) * 256 + k];
  }
  __syncthreads();
  for (int nt = 0; nt < 4; ++nt) {
    f32x4 acc = {0.f, 0.f, 0.f, 0.f};
#pragma unroll
    for (int ks = 0; ks < 8; ++ks) {
      f16x8 bfr = *(const f16x8*)&stT[(nt * 16 + c0) * 264 + ks * 32 + qd * 8];
      acc = __builtin_amdgcn_mfma_f32_16x16x32_f16(whfr[ks], bfr, acc, 0, 0, 0);
    }
#pragma unroll
    for (int q = 0; q < 4; ++q)
      hxl[(wave * 16 + qd * 4 + q) * 66 + nt * 16 + c0] = acc[q] + bh[wave * 16 + qd * 4 + q];
  }
  __syncthreads();
  if (tid < 64) {
    float s = 0.f;
    for (int j = 0; j < 64; ++j) s += hxl[tid * 66 + j];
    hxm[tid] = s * (1.f / 64.f);
  }
  __syncthreads();
  {
    f16* HAf = (f16*)U;
    for (int idx = tid; idx < 4096; idx += 256) {
      int m = idx >> 6, j = idx & 63;
      HAf[m * 72 + j] = (f16)(hxl[m * 66 + j] - hxm[m]);
    }
    __syncthreads();
    f16x8 afr[2];
#pragma unroll
    for (int ks = 0; ks < 2; ++ks)
      afr[ks] = *(const f16x8*)&HAf[(wave * 16 + c0) * 72 + ks * 32 + qd * 8];
    for (int nt = 0; nt < 4; ++nt) {
      f32x4 acc = {0.f, 0.f, 0.f, 0.f};
#pragma unroll
      for (int ks = 0; ks < 2; ++ks) {
        f16x8 bfr = *(const f16x8*)&HAf[(nt * 16 + c0) * 72 + ks * 32 + qd * 8];
        acc = __builtin_amdgcn_mfma_f32_16x16x32_f16(afr[ks], bfr, acc, 0, 0, 0);
      }
#pragma unroll
      for (int q = 0; q < 4; ++q) {
        int m1 = wave * 16 + qd * 4 + q, m2 = nt * 16 + c0;
        Pm[m1 * 65 + m2] = acc[q] * (1.f / 63.f) + (m1 == m2 ? r2 : 0.f);
      }
    }
  }
  __syncthreads();

  // ---- phase 2: blocked LDL^T factor + blocked 64-RHS solve + T = HA^T sol
  {
    float* R = (float*)U;
    f16* HAT = (f16*)(U + 16384);
    f16* solT = (f16*)(U + 25600);
    for (int idx = tid; idx < 4096; idx += 256) {
      int m = idx >> 6, j = idx & 63;
      float hv = hxl[m * 66 + j];
      R[idx] = y[b * 64 + m] - hv;
      HAT[j * 72 + m] = (f16)(hv - hxm[m]);
    }
    __syncthreads();
    ldl_factor8(Pm, tid);
    if (tid < 64) dinv[tid] = __builtin_amdgcn_rcpf(Pm[tid * 65 + tid]);
    __syncthreads();
    // forward (unit-L), 8-col blocks
    for (int i0 = 0; i0 < 64; i0 += 8) {
      if (wave == 0) {
        float rl[8];
#pragma unroll
        for (int d = 0; d < 8; ++d) rl[d] = R[(i0 + d) * 64 + n];
#pragma unroll
        for (int a = 1; a < 8; ++a)
#pragma unroll
          for (int bq = 0; bq < a; ++bq)
            rl[a] -= Pm[(i0 + a) * 65 + i0 + bq] * dinv[i0 + bq] * rl[bq];
#pragma unroll
        for (int d = 1; d < 8; ++d) R[(i0 + d) * 64 + n] = rl[d];
      }
      __syncthreads();
      for (int m = i0 + 8 + mg; m < 64; m += 4) {
        float s = R[m * 64 + n];
#pragma unroll
        for (int d = 0; d < 8; ++d)
          s -= Pm[m * 65 + i0 + d] * dinv[i0 + d] * R[(i0 + d) * 64 + n];
        R[m * 64 + n] = s;
      }
      __syncthreads();
    }
    for (int idx = tid; idx < 4096; idx += 256) R[idx] *= dinv[idx >> 6];
    __syncthreads();
    // backward (L^T), 8-col blocks descending
    for (int i0 = 56; i0 >= 0; i0 -= 8) {
      if (wave == 0) {
        float rl[8];
#pragma unroll
        for (int d = 0; d < 8; ++d) rl[d] = R[(i0 + d) * 64 + n];
#pragma unroll
        for (int a = 6; a >= 0; --a)
#pragma unroll
          for (int bq = 7; bq > a; --bq)
            rl[a] -= Pm[(i0 + bq) * 65 + i0 + a] * dinv[i0 + a] * rl[bq];
#pragma unroll
        for (int d = 0; d < 7; ++d) R[(i0 + d) * 64 + n] = rl[d];
      }
      __syncthreads();
      for (int m = mg; m < i0; m += 4) {
        float s = R[m * 64 + n];
        float dm = dinv[m];
#pragma unroll
        for (int d = 0; d < 8; ++d)
          s -= Pm[(i0 + d) * 65 + m] * dm * R[(i0 + d) * 64 + n];
        R[m * 64 + n] = s;
      }
      __syncthreads();
    }
    for (int idx = tid; idx < 4096; idx += 256) {
      int m = idx >> 6, j = idx & 63;
      solT[j * 72 + m] = (f16)R[m * 64 + j];
    }
    __syncthreads();
    f16x8 afr[2];
#pragma unroll
    for (int ks = 0; ks < 2; ++ks)
      afr[ks] = *(const f16x8*)&HAT[(wave * 16 + c0) * 72 + ks * 32 + qd * 8];
    for (int nt = 0; nt < 4; ++nt) {
      f32x4 acc = {0.f, 0.f, 0.f, 0.f};
#pragma unroll
      for (int ks = 0; ks < 2; ++ks) {
        f16x8 bfr = *(const f16x8*)&solT[(nt * 16 + c0) * 72 + ks * 32 + qd * 8];
        acc = __builtin_amdgcn_mfma_f32_16x16x32_f16(afr[ks], bfr, acc, 0, 0, 0);
      }
#pragma unroll
      for (int q = 0; q < 4; ++q) {
        int jp = wave * 16 + qd * 4 + q, j = nt * 16 + c0;
        TT[j * 72 + jp] = (f16)(acc[q] * (1.f / 63.f));
      }
    }
  }
  __syncthreads();

  // ---- phase 3: state_out = stateF + A @ TT
  {
    f16* Af = (f16*)U;
    for (int idx = tid; idx < NH * NE; idx += 256) {
      int j = idx >> 8, k = idx & 255;
      Af[k * 72 + j] = (f16)stateF2[((size_t)j * 32 + b) * 256 + k];
    }
    __syncthreads();
    {
      float s = 0.f;
      for (int j = 0; j < 64; ++j) s += (float)Af[tid * 72 + j];
      srm[tid] = s * (1.f / 64.f);
    }
    __syncthreads();
    for (int idx = tid; idx < NH * NE; idx += 256) {
      int nh = idx >> 6, j = idx & 63;
      Af[nh * 72 + j] = (f16)((float)Af[nh * 72 + j] - srm[nh]);
    }
    __syncthreads();
    f16x8 bfr[4][2];
#pragma unroll
    for (int nt = 0; nt < 4; ++nt)
#pragma unroll
      for (int ks = 0; ks < 2; ++ks)
        bfr[nt][ks] = *(const f16x8*)&TT[(nt * 16 + c0) * 72 + ks * 32 + qd * 8];
    for (int mt0 = 0; mt0 < 4; ++mt0) {
      int mt = wave * 4 + mt0;
      f16x8 afr[2];
#pragma unroll
      for (int ks = 0; ks < 2; ++ks)
        afr[ks] = *(const f16x8*)&Af[(mt * 16 + c0) * 72 + ks * 32 + qd * 8];
#pragma unroll
      for (int nt = 0; nt < 4; ++nt) {
        f32x4 acc = {0.f, 0.f, 0.f, 0.f};
#pragma unroll
        for (int ks = 0; ks < 2; ++ks)
          acc = __builtin_amdgcn_mfma_f32_16x16x32_f16(afr[ks], bfr[nt][ks], acc, 0, 0, 0);
#pragma unroll
        for (int q = 0; q < 4; ++q) {
          int m = mt * 16 + qd * 4 + q, j = nt * 16 + c0;
          float v = (float)Af[m * 72 + j] + srm[m] + acc[q];
          state_out[b * (NH * NE) + m * 64 + j] = v;
          stT[j * 264 + m] = (f16)v;
        }
      }
    }
  }
  __syncthreads();

  // ---- phase 4: mu/sig on updated state
  for (int nt = 0; nt < 4; ++nt) {
    f32x4 acc = {0.f, 0.f, 0.f, 0.f};
#pragma unroll
    for (int ks = 0; ks < 8; ++ks) {
      f16x8 bfr = *(const f16x8*)&stT[(nt * 16 + c0) * 264 + ks * 32 + qd * 8];
      acc = __builtin_amdgcn_mfma_f32_16x16x32_f16(whfr[ks], bfr, acc, 0, 0, 0);
    }
#pragma unroll
    for (int q = 0; q < 4; ++q)
      hxl[(wave * 16 + qd * 4 + q) * 66 + nt * 16 + c0] = acc[q] + bh[wave * 16 + qd * 4 + q];
  }
  __syncthreads();
  if (tid < 64) {
    float s = 0.f;
    for (int j = 0; j < 64; ++j) s += hxl[tid * 66 + j];
    s *= (1.f / 64.f);
    hxm[tid] = s;
    mu_out[b * MOBS + tid] = s;
  }
  __syncthreads();
  {
    f16* HAf = (f16*)U;
    for (int idx = tid; idx < 4096; idx += 256) {
      int m = idx >> 6, j = idx & 63;
      HAf[m * 72 + j] = (f16)(hxl[m * 66 + j] - hxm[m]);
    }
    __syncthreads();
    f16x8 afr[2];
#pragma unroll
    for (int ks = 0; ks < 2; ++ks)
      afr[ks] = *(const f16x8*)&HAf[(wave * 16 + c0) * 72 + ks * 32 + qd * 8];
    for (int nt = 0; nt < 4; ++nt) {
      f32x4 acc = {0.f, 0.f, 0.f, 0.f};
#pragma unroll
      for (int ks = 0; ks < 2; ++ks) {
        f16x8 bfr = *(const f16x8*)&HAf[(nt * 16 + c0) * 72 + ks * 32 + qd * 8];
        acc = __builtin_amdgcn_mfma_f32_16x16x32_f16(afr[ks], bfr, acc, 0, 0, 0);
      }
#pragma unroll
      for (int q = 0; q < 4; ++q) {
        int m1 = wave * 16 + qd * 4 + q, m2 = nt * 16 + c0;
        float v = acc[q] * (1.f / 63.f) + (m1 == m2 ? r2 : 0.f);
        sig_out[b * (MOBS * MOBS) + m1 * MOBS + m2] = v;
        Pm[m1 * 65 + m2] = v + (m1 == m2 ? 1e-6f : 0.f);
      }
    }
  }
  __syncthreads();

  // ---- phase 5: loglik — blocked factor, then wave-sync shfl solve
  ldl_factor8(Pm, tid);
  if (tid < 64) dinv[tid] = __builtin_amdgcn_rcpf(Pm[tid * 65 + tid]);
  __syncthreads();
  if (wave == 0) {
    const int m = lane;
    float rm = y[b * 64 + m] - hxm[m];
    const float r0 = rm;
    for (int i = 0; i < 63; ++i) {
      float xi = __shfl(rm, i);
      if (m > i) rm -= Pm[m * 65 + i] * dinv[i] * xi;
    }
    rm *= dinv[m];
    for (int i = 63; i >= 1; --i) {
      float xi = __shfl(rm, i);
      if (m < i) rm -= Pm[i * 65 + m] * dinv[m] * xi;
    }
    float prod = r0 * rm;
    float ld = __logf(Pm[m * 65 + m]);
#pragma unroll
    for (int off = 32; off; off >>= 1) {
      prod += __shfl_down(prod, off);
      ld += __shfl_down(ld, off);
    }
    if (m == 0) {
      atomicAdd(l_out, -0.5f * (ld + prod));
      atomicAdd(nis_out, prod * (1.f / 32.f));
    }
  }
}

extern "C" void kernel_launch(void* const* d_in, const int* in_sizes, int n_in,
                              void* d_out, int out_size, void* d_ws, size_t ws_size,
                              hipStream_t stream) {
  (void)in_sizes; (void)n_in; (void)out_size; (void)ws_size;
  const float* x     = (const float*)d_in[0];
  const float* y     = (const float*)d_in[1];
  const float* enkf  = (const float*)d_in[2];
  const float* W_ih  = (const float*)d_in[3];
  const float* W_hh  = (const float*)d_in[4];
  const float* bvec  = (const float*)d_in[5];
  const float* Wh    = (const float*)d_in[6];
  const float* bh    = (const float*)d_in[7];
  const float* qp    = (const float*)d_in[8];
  const float* ep    = (const float*)d_in[9];
  const float* rp    = (const float*)d_in[10];
  const float* eps_h = (const float*)d_in[11];
  const float* eps_c = (const float*)d_in[12];

  char* ws = (char*)d_ws;
  h4*    xwH     = (h4*)(ws);                   // 4,194,304
  f16*   Wpack   = (f16*)(ws + 4194304);        //   524,288
  f16*   WpackIh = (f16*)(ws + 4718592);        //   524,288
  f16*   WhfP    = (f16*)(ws + 5242880);        //    32,768
  float* stateF2 = (float*)(ws + 5275648);      // 2,097,152

  float* out = (float*)d_out;
  float* mu_out    = out;           // 2048
  float* sig_out   = out + 2048;    // 131072
  float* state_out = out + 133120;  // 524288
  float* l_out     = out + 657408;
  float* nis_out   = out + 657409;

  k_pack<<<33, 256, 0, stream>>>(W_hh, W_ih, Wh, Wpack, WpackIh, WhfP,
                                 l_out, nis_out);
  k_xw<<<128, 512, 0, stream>>>(x, WpackIh, bvec, xwH);
  k_lstm<<<64, 1024, 0, stream>>>(xwH, Wpack, enkf, eps_h, eps_c, qp, ep, stateF2);
  k_fused<<<32, 256, 0, stream>>>(stateF2, WhfP, bh, rp, y, mu_out, sig_out,
                                  state_out, l_out, nis_out);
}